// Round 1
// baseline (905.335 us; speedup 1.0000x reference)
//
#include <hip/hip_runtime.h>
#include <cstdint>

#define Tt 1024
#define Hh 15
#define Ii 10
#define Oo 128
#define Bb 512

#define NPROD 32            // producer blocks (4 waves each -> 128 producer waves)
#define CH    128           // time steps per completion signal
#define NSIG  128           // producer waves that sign each chunk

typedef float v4f __attribute__((ext_vector_type(4)));

__device__ __forceinline__ float sigmoidf_(float x) {
    return 1.0f / (1.0f + __expf(-x));
}
__device__ __forceinline__ float tanhf_(float x) {
    return 1.0f - 2.0f / (__expf(2.0f * x) + 1.0f);
}

// DPP row-rotate of a float within the 16-lane row. j must be a literal.
#define ROT(x, j) __int_as_float(__builtin_amdgcn_update_dpp( \
    0, __float_as_int(x), 0x120 + (j), 0xF, 0xF, true))

__device__ __forceinline__ v4f ntload4(const float* p) {
    return __builtin_nontemporal_load((const v4f*)p);
}

// Fused GRU: producer/consumer overlap in ONE dispatch.
//
// hs layout: [T][B][16] floats. Element 15 of each row is a pad slot the
// projection never uses. Control words live in t=0 pad slots:
//   ctl[0*16+15]        = block ticket
//   ctl[(1+c)*16+15]    = done counter for chunk c (c = t/CH, 8 chunks)
// Producer lane-15 junk stores are redirected to pad rows 64..319 so they
// can never touch the control words.
//
// Deadlock-freedom: roles are assigned by atomic ticket, so the first 32
// blocks that RUN become producers (they are resident by definition) and
// producers never wait on consumers. Worst-case schedule degenerates to
// the old sequential two-kernel behavior.
__global__ __launch_bounds__(256) void gru_fused(
    const float* __restrict__ feed, const float* __restrict__ h0,
    const float* __restrict__ W_ih, const float* __restrict__ W_hh,
    const float* __restrict__ b_ih, const float* __restrict__ b_hh,
    const float* __restrict__ W_out, const float* __restrict__ b_out,
    float* __restrict__ out, float* __restrict__ hs)
{
    int* ctl = (int*)hs;
    __shared__ int s_ticket;
    if (threadIdx.x == 0)
        s_ticket = atomicAdd(ctl + 15, 1);
    __syncthreads();
    const int bt = s_ticket;
    const int tid = threadIdx.x;

    if (bt < NPROD) {
        // ---------------- producer: sequential recurrence ----------------
        const int lane = tid & 63;
        const int wv   = tid >> 6;          // wave in block, 0..3
        const int g    = lane >> 4;         // batch group = DPP row
        const int u    = lane & 15;         // hidden unit (u==15 inert)
        const int uu   = (u < Hh) ? u : 0;
        const int b    = bt * 16 + wv * 4 + g;

        // Probe DPP row_ror source direction once.
        int pr = __builtin_amdgcn_update_dpp(0, lane & 15, 0x121, 0xF, 0xF, true);
        int p0 = __builtin_amdgcn_readfirstlane(pr);
        const int dir = (p0 == 1) ? 1 : 15;     // 15*j == -j (mod 16)

        float Wr[16], Wz[16], Wn[16];
        #pragma unroll
        for (int j = 0; j < 16; ++j) {
            int k = (uu + dir * j) & 15;
            bool ok = (k < Hh);
            int kk = ok ? k : 0;
            Wr[j] = ok ? W_hh[(uu         ) * Hh + kk] : 0.0f;
            Wz[j] = ok ? W_hh[(uu +     Hh) * Hh + kk] : 0.0f;
            Wn[j] = ok ? W_hh[(uu + 2 * Hh) * Hh + kk] : 0.0f;
        }

        float cr = b_ih[uu]          + b_hh[uu];
        float cz = b_ih[uu + Hh]     + b_hh[uu + Hh];
        float cn = b_ih[uu + 2 * Hh];
        float bn = b_hh[uu + 2 * Hh];
        #pragma unroll
        for (int i = 0; i < Ii; ++i) {
            float x = feed[b * Ii + i];
            cr += x * W_ih[(uu         ) * Ii + i];
            cz += x * W_ih[(uu +     Hh) * Ii + i];
            cn += x * W_ih[(uu + 2 * Hh) * Ii + i];
        }

        float hcur = (u < Hh) ? h0[b * Hh + uu] : 0.0f;
        // Inert lane parks its junk store in pad rows 64..319 (never rows 0..8,
        // which hold the control words).
        size_t off = (u < Hh) ? ((size_t)b * 16 + u)
                              : ((size_t)(64 + (b & 255)) * 16 + 15);

        for (int t = 0; t < Tt; ++t) {
            float hr[16];
            hr[0]  = hcur;
            hr[1]  = ROT(hcur, 1);   hr[2]  = ROT(hcur, 2);
            hr[3]  = ROT(hcur, 3);   hr[4]  = ROT(hcur, 4);
            hr[5]  = ROT(hcur, 5);   hr[6]  = ROT(hcur, 6);
            hr[7]  = ROT(hcur, 7);   hr[8]  = ROT(hcur, 8);
            hr[9]  = ROT(hcur, 9);   hr[10] = ROT(hcur, 10);
            hr[11] = ROT(hcur, 11);  hr[12] = ROT(hcur, 12);
            hr[13] = ROT(hcur, 13);  hr[14] = ROT(hcur, 14);
            hr[15] = ROT(hcur, 15);

            float ar[4] = {cr, 0.f, 0.f, 0.f};
            float az[4] = {cz, 0.f, 0.f, 0.f};
            float an[4] = {bn, 0.f, 0.f, 0.f};
            #pragma unroll
            for (int j = 0; j < 16; ++j) {
                ar[j & 3] += Wr[j] * hr[j];
                az[j & 3] += Wz[j] * hr[j];
                an[j & 3] += Wn[j] * hr[j];
            }
            float r = sigmoidf_((ar[0] + ar[1]) + (ar[2] + ar[3]));
            float z = sigmoidf_((az[0] + az[1]) + (az[2] + az[3]));
            float dn = (an[0] + an[1]) + (an[2] + an[3]);
            float n = tanhf_(cn + r * dn);
            float hnew = n + z * (hcur - n);

            hs[off] = hnew;
            off += (size_t)Bb * 16;
            hcur = hnew;

            if ((t & (CH - 1)) == (CH - 1)) {
                // Release: drain stores + write back this XCD's L2 so the
                // chunk is visible at the device-coherent point, then sign.
                __threadfence();
                if ((tid & 63) == 0)
                    atomicAdd(ctl + (1 + (t >> 7)) * 16 + 15, 1);
            }
        }
    } else {
        // ---------------- consumer: projection for one time step ----------------
        const int t  = bt - NPROD;          // 0..1023
        const int q  = tid & 31;            // o-quad
        const int gg = tid >> 5;            // b-slot within block (0..7)
        const int o0 = q * 4;

        float w[4][Hh];
        float bo[4];
        #pragma unroll
        for (int j = 0; j < 4; ++j) {
            bo[j] = b_out[o0 + j];
            #pragma unroll
            for (int k = 0; k < Hh; ++k) w[j][k] = W_out[(o0 + j) * Hh + k];
        }

        // Wait for all 128 producer waves to finish this chunk. Poll with a
        // device-scope atomic load (bypasses the possibly-stale local L2),
        // throttled with s_sleep; only thread 0 polls.
        int* done = ctl + (1 + (t >> 7)) * 16 + 15;
        if (tid == 0) {
            while (__hip_atomic_load(done, __ATOMIC_RELAXED,
                                     __HIP_MEMORY_SCOPE_AGENT) < NSIG)
                __builtin_amdgcn_s_sleep(32);
        }
        __syncthreads();
        __threadfence();   // acquire: invalidate local caches before reading hs

        const float* base  = hs  + (size_t)t * (Bb * 16);
        float*       obase = out + (size_t)t * ((size_t)Bb * Oo);

        int b = gg;
        const float* hp = base + (size_t)b * 16;
        v4f A = ntload4(hp), B_ = ntload4(hp + 4),
            C = ntload4(hp + 8), D = ntload4(hp + 12);

        #pragma unroll 2
        for (int it = 0; it < Bb / 8; ++it) {
            int bnx = b + 8;
            bool more = (it < Bb / 8 - 1);
            const float* hq = base + (size_t)(more ? bnx : b) * 16;
            v4f A2 = ntload4(hq), B2 = ntload4(hq + 4),
                C2 = ntload4(hq + 8), D2 = ntload4(hq + 12);

            float h[Hh] = {A.x, A.y, A.z, A.w, B_.x, B_.y, B_.z, B_.w,
                           C.x, C.y, C.z, C.w, D.x, D.y, D.z};
            float acc[4];
            #pragma unroll
            for (int j = 0; j < 4; ++j) {
                float s0 = bo[j], s1 = 0.f;
                #pragma unroll
                for (int k = 0; k < Hh; k += 2) s0 += h[k] * w[j][k];
                #pragma unroll
                for (int k = 1; k < Hh; k += 2) s1 += h[k] * w[j][k];
                acc[j] = sigmoidf_(s0 + s1);
            }
            v4f res = {acc[0], acc[1], acc[2], acc[3]};
            __builtin_nontemporal_store(res, (v4f*)(obase + (size_t)b * Oo + o0));

            b = bnx; A = A2; B_ = B2; C = C2; D = D2;
        }
    }
}

extern "C" void kernel_launch(void* const* d_in, const int* in_sizes, int n_in,
                              void* d_out, int out_size, void* d_ws, size_t ws_size,
                              hipStream_t stream) {
    const float* feed  = (const float*)d_in[0];
    const float* h0    = (const float*)d_in[1];
    const float* W_ih  = (const float*)d_in[2];
    const float* W_hh  = (const float*)d_in[3];
    const float* b_ih  = (const float*)d_in[4];
    const float* b_hh  = (const float*)d_in[5];
    const float* W_out = (const float*)d_in[6];
    const float* b_out = (const float*)d_in[7];
    float* out = (float*)d_out;
    float* hs  = (float*)d_ws;   // [T][B][16] floats = 33.5 MB

    // Zero the control words (ticket + done[] live in t=0 pad slots).
    hipMemsetAsync(d_ws, 0, 1024, stream);
    gru_fused<<<NPROD + Tt, 256, 0, stream>>>(
        feed, h0, W_ih, W_hh, b_ih, b_hh, W_out, b_out, out, hs);
}

// Round 3
// 856.421 us; speedup vs baseline: 1.0571x; 1.0571x over previous
//
#include <hip/hip_runtime.h>
#include <cstdint>

#define Tt 1024
#define Hh 15
#define Ii 10
#define Oo 128
#define Bb 512

typedef float v4f __attribute__((ext_vector_type(4)));
typedef float v2f __attribute__((ext_vector_type(2)));

__device__ __forceinline__ float sigmoidf_(float x) {
    return 1.0f / (1.0f + __expf(-x));
}
__device__ __forceinline__ float tanhf_(float x) {
    return 1.0f - 2.0f / (__expf(2.0f * x) + 1.0f);
}

// DPP row-rotate of a float within the 16-lane row. j must be a literal.
#define ROT(x, j) __int_as_float(__builtin_amdgcn_update_dpp( \
    0, __float_as_int(x), 0x120 + (j), 0xF, 0xF, true))

#define ROTALL(dst, src)                                        \
    dst[0]  = (src);                                            \
    dst[1]  = ROT(src, 1);   dst[2]  = ROT(src, 2);             \
    dst[3]  = ROT(src, 3);   dst[4]  = ROT(src, 4);             \
    dst[5]  = ROT(src, 5);   dst[6]  = ROT(src, 6);             \
    dst[7]  = ROT(src, 7);   dst[8]  = ROT(src, 8);             \
    dst[9]  = ROT(src, 9);   dst[10] = ROT(src, 10);            \
    dst[11] = ROT(src, 11);  dst[12] = ROT(src, 12);            \
    dst[13] = ROT(src, 13);  dst[14] = ROT(src, 14);            \
    dst[15] = ROT(src, 15);

// Single fused kernel: 1 wave/block, 4 batch elems/wave, 16 lanes (one DPP
// row) per batch elem; lane u owns hidden unit u (u==15 inert for the
// recurrence, but ACTIVE for the projection).
//
// Recurrence (bit-identical to the 527us passing kernel):
//   (W h)[u] = sum_j W[u][(u+dir*j)&15] * row_ror_j(h), k==15 taps zeroed.
//
// Projection fused into the recurrence's dependency-stall slots:
//   After rotating hnew (needed for step t+1 anyway), EVERY lane holds all
//   15 valid h-values (the one junk tap, k==15, is weight-zeroed). Lane u
//   computes outputs o = u*8 .. u*8+7 with a per-lane rotated W_out table
//   (128 VGPRs; __launch_bounds__(64,1) gives us up to 512). Per 16-lane
//   group the 8-float stores are 512B contiguous; the wave's 4 groups are
//   4 consecutive batches -> 2KB contiguous nontemporal store per step.
//   No hs workspace, no second kernel, no inter-block sync.
__global__ __launch_bounds__(64, 1) void gru_fused(
    const float* __restrict__ feed, const float* __restrict__ h0,
    const float* __restrict__ W_ih, const float* __restrict__ W_hh,
    const float* __restrict__ b_ih, const float* __restrict__ b_hh,
    const float* __restrict__ W_out, const float* __restrict__ b_out,
    float* __restrict__ out)
{
    const int lane = threadIdx.x;      // 0..63
    const int g = lane >> 4;           // batch group = DPP row
    const int u = lane & 15;           // hidden unit (u==15 inert in recur)
    const int uu = (u < Hh) ? u : 0;
    const int b = blockIdx.x * 4 + g;

    // Probe DPP row_ror source direction once.
    int pr = __builtin_amdgcn_update_dpp(0, lane & 15, 0x121, 0xF, 0xF, true);
    int p0 = __builtin_amdgcn_readfirstlane(pr);
    const int dir = (p0 == 1) ? 1 : 15;   // 15*j == -j (mod 16)

    // Rotated recurrence weight tables (k==15 slots zeroed).
    float Wr[16], Wz[16], Wn[16];
    #pragma unroll
    for (int j = 0; j < 16; ++j) {
        int k = (uu + dir * j) & 15;
        bool ok = (k < Hh);
        int kk = ok ? k : 0;
        Wr[j] = ok ? W_hh[(uu         ) * Hh + kk] : 0.0f;
        Wz[j] = ok ? W_hh[(uu +     Hh) * Hh + kk] : 0.0f;
        Wn[j] = ok ? W_hh[(uu + 2 * Hh) * Hh + kk] : 0.0f;
    }

    // Rotated projection weight table: lane u owns outputs u*8 .. u*8+7.
    // Uses the TRUE u (all 16 lanes active). Packed in j-pairs for pk-FMA.
    v2f Wo[8][8];
    float bo[8];
    #pragma unroll
    for (int m = 0; m < 8; ++m) {
        bo[m] = b_out[u * 8 + m];
        #pragma unroll
        for (int jp = 0; jp < 8; ++jp) {
            float w0, w1;
            {
                int k = (u + dir * (2 * jp)) & 15;
                w0 = (k < Hh) ? W_out[(u * 8 + m) * Hh + k] : 0.0f;
            }
            {
                int k = (u + dir * (2 * jp + 1)) & 15;
                w1 = (k < Hh) ? W_out[(u * 8 + m) * Hh + k] : 0.0f;
            }
            Wo[m][jp] = (v2f){w0, w1};
        }
    }

    // Time-invariant input-gate constants.
    float cr = b_ih[uu]          + b_hh[uu];
    float cz = b_ih[uu + Hh]     + b_hh[uu + Hh];
    float cn = b_ih[uu + 2 * Hh];
    float bn = b_hh[uu + 2 * Hh];
    #pragma unroll
    for (int i = 0; i < Ii; ++i) {
        float x = feed[b * Ii + i];
        cr += x * W_ih[(uu         ) * Ii + i];
        cz += x * W_ih[(uu +     Hh) * Ii + i];
        cn += x * W_ih[(uu + 2 * Hh) * Ii + i];
    }

    float hcur = (u < Hh) ? h0[b * Hh + uu] : 0.0f;

    float hr[16];
    ROTALL(hr, hcur);

    float* op = out + (size_t)b * Oo + (size_t)u * 8;

    for (int t = 0; t < Tt; ++t) {
        // ---- recurrence gates from hr (bit-identical to passing kernel) ----
        float ar[4] = {cr, 0.f, 0.f, 0.f};
        float az[4] = {cz, 0.f, 0.f, 0.f};
        float an[4] = {bn, 0.f, 0.f, 0.f};
        #pragma unroll
        for (int j = 0; j < 16; ++j) {
            ar[j & 3] += Wr[j] * hr[j];
            az[j & 3] += Wz[j] * hr[j];
            an[j & 3] += Wn[j] * hr[j];
        }
        float r = sigmoidf_((ar[0] + ar[1]) + (ar[2] + ar[3]));
        float z = sigmoidf_((az[0] + az[1]) + (az[2] + az[3]));
        float dn = (an[0] + an[1]) + (an[2] + an[3]);
        float n = tanhf_(cn + r * dn);
        float hnew = n + z * (hcur - n);

        // ---- rotate hnew: feeds BOTH the next step and this step's proj ----
        ROTALL(hr, hnew);
        hcur = hnew;

        // ---- fused projection for this step: out[t][b][u*8 .. u*8+7] ----
        // 64 packed FMAs + 8 sigmoids; independent of the next step's gate
        // chain -> fills its stall slots.
        v2f h2[8];
        #pragma unroll
        for (int jp = 0; jp < 8; ++jp)
            h2[jp] = (v2f){hr[2 * jp], hr[2 * jp + 1]};

        float o8[8];
        #pragma unroll
        for (int m = 0; m < 8; ++m) {
            v2f a = (v2f){bo[m], 0.0f};
            #pragma unroll
            for (int jp = 0; jp < 8; ++jp)
                a += Wo[m][jp] * h2[jp];
            o8[m] = sigmoidf_(a.x + a.y);
        }

        v4f lo = {o8[0], o8[1], o8[2], o8[3]};
        v4f hi = {o8[4], o8[5], o8[6], o8[7]};
        __builtin_nontemporal_store(lo, (v4f*)op);
        __builtin_nontemporal_store(hi, (v4f*)(op + 4));
        op += (size_t)Bb * Oo;
    }
}

extern "C" void kernel_launch(void* const* d_in, const int* in_sizes, int n_in,
                              void* d_out, int out_size, void* d_ws, size_t ws_size,
                              hipStream_t stream) {
    const float* feed  = (const float*)d_in[0];
    const float* h0    = (const float*)d_in[1];
    const float* W_ih  = (const float*)d_in[2];
    const float* W_hh  = (const float*)d_in[3];
    const float* b_ih  = (const float*)d_in[4];
    const float* b_hh  = (const float*)d_in[5];
    const float* W_out = (const float*)d_in[6];
    const float* b_out = (const float*)d_in[7];
    float* out = (float*)d_out;
    (void)d_ws;

    gru_fused<<<Bb / 4, 64, 0, stream>>>(
        feed, h0, W_ih, W_hh, b_ih, b_hh, W_out, b_out, out);
}